// Round 3
// baseline (175.526 us; speedup 1.0000x reference)
//
#include <hip/hip_runtime.h>
#include <stdint.h>

#define Bn 8
#define Nn 1024
#define Fn 64
#define Tn 32
#define Kn 3
#define On 64
#define Rn (Kn * Nn)   // 3072 reduction dim (k,j)
#define Cn (On * Tn)   // 2048 output cols (o,t)
#define NT (Rn / 64)   // 48 K-tiles of BK=64

typedef __bf16 bf16x8 __attribute__((ext_vector_type(8)));
typedef float f32x4 __attribute__((ext_vector_type(4)));
typedef __attribute__((address_space(1))) void gvoid;
typedef __attribute__((address_space(3))) void lvoid;

union BF8 { bf16x8 v; ushort s[8]; uint4 q; };

static __device__ __forceinline__ ushort f2bf(float f) {
  uint32_t u = __float_as_uint(f);
  return (ushort)((u + 0x7FFFu + ((u >> 16) & 1u)) >> 16);
}

static __device__ __forceinline__ void glds(const ushort* g, ushort* l) {
  __builtin_amdgcn_global_load_lds((gvoid*)g, (lvoid*)l, 16, 0, 0);
}

// K0: ThetaT[k][o][f] = Theta[k][f][o], bf16
__global__ void k_thetaT(const float* __restrict__ Theta, ushort* __restrict__ ThT) {
  int idx = blockIdx.x * 256 + threadIdx.x;
  if (idx < Kn * On * Fn) {
    int k = idx / (On * Fn);
    int rem = idx % (On * Fn);
    int o = rem / Fn, f = rem % Fn;
    ThT[idx] = f2bf(Theta[(k * Fn + f) * On + o]);
  }
}

// K1: W_T[b][i][k*Nn + j] = cheb[k][j][i] * att[b][j][i], bf16.
// b-loop inside block: cheb tile read ONCE (12 MB total, not 96).
__global__ __launch_bounds__(256) void k_prepW(const float* __restrict__ att,
                                               const float* __restrict__ cheb,
                                               ushort* __restrict__ Wt) {
  __shared__ float tile[32][33];
  int i0 = blockIdx.x * 32, j0 = blockIdx.y * 32;
  int tid = threadIdx.x;
  int ci = tid & 31, rj = tid >> 5;  // 8 rows per pass
  float cv[4][Kn];
#pragma unroll
  for (int p = 0; p < 4; p++) {
    int j = j0 + rj + p * 8;
#pragma unroll
    for (int k = 0; k < Kn; k++)
      cv[p][k] = cheb[((size_t)k * Nn + j) * Nn + i0 + ci];
  }
  for (int b = 0; b < Bn; b++) {
    float av[4];
#pragma unroll
    for (int p = 0; p < 4; p++) {
      int j = j0 + rj + p * 8;
      av[p] = att[((size_t)b * Nn + j) * Nn + i0 + ci];
    }
    for (int k = 0; k < Kn; k++) {
#pragma unroll
      for (int p = 0; p < 4; p++)
        tile[rj + p * 8][ci] = av[p] * cv[p][k];
      __syncthreads();
#pragma unroll
      for (int p = 0; p < 4; p++) {
        int i = i0 + rj + p * 8;  // ci now indexes j
        Wt[((size_t)b * Nn + i) * Rn + (size_t)k * Nn + j0 + ci] = f2bf(tile[ci][rj + p * 8]);
      }
      __syncthreads();
    }
  }
}

// K2: Y_T[b][c][k*Nn + j] = sum_f ThetaT[k][o][f] * x[b][j][f][t],  c = o*Tn + t
__global__ __launch_bounds__(512) void k_prepY(const float* __restrict__ x,
                                               const ushort* __restrict__ ThT,
                                               ushort* __restrict__ Yt) {
  __shared__ ushort ylds[1024 * 32];  // 64 KB: [c_local][j_slot]
  int jt = blockIdx.x, b = blockIdx.y;
  int j0 = jt * 32;
  int tid = threadIdx.x;
  int lane = tid & 63, w = tid >> 6;
  int l15 = lane & 15, l4 = lane >> 4;

  BF8 bfr[4][2][2];
#pragma unroll
  for (int jj = 0; jj < 4; jj++) {
    const float* xp = x + ((size_t)b * Nn + (j0 + w * 4 + jj)) * (Fn * Tn);
#pragma unroll
    for (int ks = 0; ks < 2; ks++)
#pragma unroll
      for (int tf = 0; tf < 2; tf++) {
        int t = tf * 16 + l15;
        int fb = ks * 32 + l4 * 8;
#pragma unroll
        for (int e = 0; e < 8; e++)
          bfr[jj][ks][tf].s[e] = f2bf(xp[(fb + e) * Tn + t]);
      }
  }

  for (int k = 0; k < Kn; k++) {
    for (int h = 0; h < 2; h++) {  // o-half
      BF8 afr[2][2];
#pragma unroll
      for (int o2 = 0; o2 < 2; o2++)
#pragma unroll
        for (int ks = 0; ks < 2; ks++) {
          int o = h * 32 + o2 * 16 + l15;
          afr[o2][ks].q = *(const uint4*)&ThT[((size_t)k * On + o) * Fn + ks * 32 + l4 * 8];
        }
#pragma unroll
      for (int jj = 0; jj < 4; jj++) {
        f32x4 acc[2][2] = {};
#pragma unroll
        for (int ks = 0; ks < 2; ks++)
#pragma unroll
          for (int o2 = 0; o2 < 2; o2++)
#pragma unroll
            for (int tf = 0; tf < 2; tf++)
              acc[o2][tf] = __builtin_amdgcn_mfma_f32_16x16x32_bf16(
                  afr[o2][ks].v, bfr[jj][ks][tf].v, acc[o2][tf], 0, 0, 0);
#pragma unroll
        for (int o2 = 0; o2 < 2; o2++)
#pragma unroll
          for (int tf = 0; tf < 2; tf++)
#pragma unroll
            for (int q = 0; q < 4; q++) {
              int cl = (o2 * 16 + l4 * 4 + q) * Tn + tf * 16 + l15;
              ylds[cl * 32 + w * 4 + jj] = f2bf(acc[o2][tf][q]);
            }
      }
      __syncthreads();
      const uint32_t* yl32 = (const uint32_t*)ylds;
      uint32_t* Yt32 = (uint32_t*)Yt;
      int e = tid & 15, rowst = tid >> 4;
      for (int pass = 0; pass < 32; pass++) {
        int cl = pass * 32 + rowst;
        size_t off = ((size_t)b * Cn + (size_t)(h * 1024 + cl)) * Rn + (size_t)k * Nn + j0;
        Yt32[off / 2 + e] = yl32[cl * 16 + e];
      }
      __syncthreads();
    }
  }
}

// K3: out[b][i][c] = relu( sum_r Wt[b][i][r] * Yt[b][c][r] )
// m201-style: 256x256 tile, BK=64, 8 waves (2Mx4N), 2-deep K-tile dbuf,
// 4 phases/tile, XOR-swizzled LDS (both-sides), counted vmcnt (never 0), setprio.
// LDS layout per operand: [buf(2)][half(2)][128 rows][64 cols] bf16, swizzled:
//   element e: stored at e ^ ((row&7)<<3) ; staged via inverse-swizzled global src.
// A-half h = tile rows {h*64..h*64+63} U {128+h*64..128+h*64+63}
// B-half h = tile cols {64g + h*32 + 0..31, g=0..3} mapped to rows of Yt.
__global__ __launch_bounds__(512, 2) void k_gemm(const ushort* __restrict__ Wt,
                                                 const ushort* __restrict__ Yt,
                                                 float* __restrict__ out) {
  extern __shared__ __align__(16) ushort smem[];
  ushort* As = smem;           // 2 bufs x 2 halves x 128x64 = 32768 ushorts
  ushort* Bs = smem + 32768;

  int g = blockIdx.x;
  int b = g & 7, slot = g >> 3;          // each b's 32 tiles on one XCD (RR heuristic)
  int i0 = (slot & 3) * 256, c0 = (slot >> 2) * 256;
  int tid = threadIdx.x, lane = tid & 63, w = tid >> 6;
  int l15 = lane & 15, l4 = lane >> 4;
  int wm = w >> 2, wn = w & 3;

  const ushort* Ab = Wt + ((size_t)b * Nn + i0) * Rn;
  const ushort* Bb = Yt + ((size_t)b * Cn + c0) * Rn;

  // staging: per (half, load L): thread covers LDS elems [w*512 + L*4096 + lane*8, +8)
  // lds row l = w*8 + (lane>>3) + L*64 ; source col chunk inverse-swizzled.
  int srcC = (((lane & 7) ^ (lane >> 3)) * 8);
  int arow0 = w * 8 + (lane >> 3);                       // + h*64 (+128 for L=1)
  int brow0 = (w >> 2) * 64 + (w & 3) * 8 + (lane >> 3); // + h*32 (+128 for L=1)

  // ds_read addressing (swizzled)
  int aL = (wm * 64 + l15) * 64;   // + (m&3)*1024 + (mh)*8192
  int bL = (wn * 32 + l15) * 64;   // + (n&1)*1024 + (nh)*8192
  int x7 = l15 & 7;
  int colx0 = ((l4) ^ x7) * 8;
  int colx1 = ((4 + l4) ^ x7) * 8;

  f32x4 acc[8][4] = {};
  BF8 af[4][2], bf[4][2];

#define MFMA_(a_, b_, c_) __builtin_amdgcn_mfma_f32_16x16x32_bf16((a_), (b_), (c_), 0, 0, 0)
#define BAR() asm volatile("s_barrier" ::: "memory")
#define PRIO1 __builtin_amdgcn_s_setprio(1)
#define PRIO0 __builtin_amdgcn_s_setprio(0)

#define STAGE_A(t_, h_) { int bo_ = ((t_) & 1) * 16384 + (h_) * 8192 + w * 512; \
    const ushort* gp_ = Ab + (size_t)(arow0 + (h_) * 64) * Rn + (t_) * 64 + srcC; \
    glds(gp_, As + bo_); \
    glds(gp_ + 128 * (size_t)Rn, As + bo_ + 4096); }
#define STAGE_B(t_, h_) { int bo_ = ((t_) & 1) * 16384 + (h_) * 8192 + w * 512; \
    const ushort* gp_ = Bb + (size_t)(brow0 + (h_) * 32) * Rn + (t_) * 64 + srcC; \
    glds(gp_, Bs + bo_); \
    glds(gp_ + 128 * (size_t)Rn, Bs + bo_ + 4096); }

#define RD_A(mh_) { _Pragma("unroll") for (int m = 0; m < 4; m++) { \
    int ba_ = bufo + (mh_) * 8192 + aL + m * 1024; \
    af[m][0].q = *(const uint4*)&As[ba_ + colx0]; \
    af[m][1].q = *(const uint4*)&As[ba_ + colx1]; } }
#define RD_B(nh_) { _Pragma("unroll") for (int n = 0; n < 2; n++) { \
    int bb_ = bufo + (nh_) * 8192 + bL + n * 1024; \
    bf[(nh_) * 2 + n][0].q = *(const uint4*)&Bs[bb_ + colx0]; \
    bf[(nh_) * 2 + n][1].q = *(const uint4*)&Bs[bb_ + colx1]; } }
#define MM(mh_, nh_) { _Pragma("unroll") for (int m = 0; m < 4; m++) \
    _Pragma("unroll") for (int n = 0; n < 2; n++) { \
      int gm_ = (mh_) * 4 + m, gn_ = (nh_) * 2 + n; \
      acc[gm_][gn_] = MFMA_(af[m][0].v, bf[gn_][0].v, acc[gm_][gn_]); \
      acc[gm_][gn_] = MFMA_(af[m][1].v, bf[gn_][1].v, acc[gm_][gn_]); } }

#define VMC(n_) asm volatile("s_waitcnt vmcnt(" #n_ ")" ::: "memory")

  // prologue: issue [Ah0(0), Bh0(0), Bh1(0), Ah1(0), Ah0(1)] = 10 loads
  STAGE_A(0, 0); STAGE_B(0, 0); STAGE_B(0, 1); STAGE_A(0, 1); STAGE_A(1, 0);
  VMC(6);   // Ah0(0), Bh0(0) landed
  BAR();

#define TILE(t_, S1_, S2_, W0_, W1_, W3_, LAST_) { \
    int bufo = ((t_) & 1) * 16384; \
    /* P0: quadrant (mh0, nh0) */ \
    RD_A(0); RD_B(0); \
    if (S1_) STAGE_B((t_) + 1, 0); \
    BAR(); \
    PRIO1; MM(0, 0); PRIO0; \
    VMC(W0_); BAR(); \
    /* P1: (mh0, nh1) */ \
    RD_B(1); \
    if (S1_) { STAGE_B((t_) + 1, 1); STAGE_A((t_) + 1, 1); } \
    BAR(); \
    PRIO1; MM(0, 1); PRIO0; \
    VMC(W1_); BAR(); \
    /* P2: (mh1, nh0) */ \
    RD_A(1); \
    if (S2_) STAGE_A((t_) + 2, 0); \
    BAR(); \
    PRIO1; MM(1, 0); PRIO0; \
    BAR(); \
    /* P3: (mh1, nh1) */ \
    PRIO1; MM(1, 1); PRIO0; \
    if (!(LAST_)) { VMC(W3_); BAR(); } \
  }

  for (int t = 0; t < NT - 2; ++t)
    TILE(t, 1, 1, 6, 8, 6, 0);
  TILE(NT - 2, 1, 0, 6, 8, 4, 0);
  TILE(NT - 1, 0, 0, 2, 0, 0, 1);

#undef TILE
#undef VMC
#undef MM
#undef RD_B
#undef RD_A
#undef STAGE_B
#undef STAGE_A

  float* ob = out + (size_t)b * Nn * Cn;
#pragma unroll
  for (int m = 0; m < 8; m++) {
    int i = i0 + wm * 128 + m * 16 + l4 * 4;
#pragma unroll
    for (int n = 0; n < 4; n++) {
      int c = c0 + wn * 64 + n * 16 + l15;
#pragma unroll
      for (int q = 0; q < 4; q++)
        ob[(size_t)(i + q) * Cn + c] = fmaxf(acc[m][n][q], 0.0f);
    }
  }
}

extern "C" void kernel_launch(void* const* d_in, const int* in_sizes, int n_in,
                              void* d_out, int out_size, void* d_ws, size_t ws_size,
                              hipStream_t stream) {
  const float* x     = (const float*)d_in[0];  // (B,N,F,T)
  const float* att   = (const float*)d_in[1];  // (B,N,N)
  const float* cheb  = (const float*)d_in[2];  // (K,N,N)
  const float* Theta = (const float*)d_in[3];  // (K,F,O)
  float* out = (float*)d_out;                  // (B,N,O,T)

  char* ws = (char*)d_ws;
  ushort* ThT = (ushort*)ws;                              // 24 KB (padded to 64 KB)
  ushort* Wt  = (ushort*)(ws + 65536);                    // 8*1024*3072*2 = 50,331,648 B
  ushort* Yt  = (ushort*)(ws + 65536 + 50331648ull);      // 8*2048*3072*2 = 100,663,296 B

  hipFuncSetAttribute((const void*)k_gemm, hipFuncAttributeMaxDynamicSharedMemorySize, 131072);

  k_thetaT<<<48, 256, 0, stream>>>(Theta, ThT);
  k_prepW<<<dim3(32, 32), 256, 0, stream>>>(att, cheb, Wt);
  k_prepY<<<dim3(32, 8), 512, 0, stream>>>(x, ThT, Yt);
  k_gemm<<<256, 512, 131072, stream>>>(Wt, Yt, out);
}

// Round 4
// 173.760 us; speedup vs baseline: 1.0102x; 1.0102x over previous
//
#include <hip/hip_runtime.h>
#include <stdint.h>

#define Bn 8
#define Nn 1024
#define Fn 64
#define Tn 32
#define Kn 3
#define On 64
#define Rn (Kn * Nn)   // 3072 reduction dim (k,j)
#define Cn (On * Tn)   // 2048 output cols (o,t)
#define NT (Rn / 64)   // 48 K-tiles of BK=64

typedef __bf16 bf16x8 __attribute__((ext_vector_type(8)));
typedef float f32x4 __attribute__((ext_vector_type(4)));
typedef __attribute__((address_space(1))) void gvoid;
typedef __attribute__((address_space(3))) void lvoid;

union BF8 { bf16x8 v; ushort s[8]; uint4 q; };

static __device__ __forceinline__ ushort f2bf(float f) {
  uint32_t u = __float_as_uint(f);
  return (ushort)((u + 0x7FFFu + ((u >> 16) & 1u)) >> 16);
}

static __device__ __forceinline__ void glds(const ushort* g, ushort* l) {
  __builtin_amdgcn_global_load_lds((gvoid*)g, (lvoid*)l, 16, 0, 0);
}

// K0: ThetaT[k][o][f] = Theta[k][f][o], bf16
__global__ void k_thetaT(const float* __restrict__ Theta, ushort* __restrict__ ThT) {
  int idx = blockIdx.x * 256 + threadIdx.x;
  if (idx < Kn * On * Fn) {
    int k = idx / (On * Fn);
    int rem = idx % (On * Fn);
    int o = rem / Fn, f = rem % Fn;
    ThT[idx] = f2bf(Theta[(k * Fn + f) * On + o]);
  }
}

// K1: W_T[b][i][k*Nn + j] = cheb[k][j][i] * att[b][j][i], bf16.
// b-loop inside block: cheb tile read ONCE.
__global__ __launch_bounds__(256) void k_prepW(const float* __restrict__ att,
                                               const float* __restrict__ cheb,
                                               ushort* __restrict__ Wt) {
  __shared__ float tile[32][33];
  int i0 = blockIdx.x * 32, j0 = blockIdx.y * 32;
  int tid = threadIdx.x;
  int ci = tid & 31, rj = tid >> 5;  // 8 rows per pass
  float cv[4][Kn];
#pragma unroll
  for (int p = 0; p < 4; p++) {
    int j = j0 + rj + p * 8;
#pragma unroll
    for (int k = 0; k < Kn; k++)
      cv[p][k] = cheb[((size_t)k * Nn + j) * Nn + i0 + ci];
  }
  for (int b = 0; b < Bn; b++) {
    float av[4];
#pragma unroll
    for (int p = 0; p < 4; p++) {
      int j = j0 + rj + p * 8;
      av[p] = att[((size_t)b * Nn + j) * Nn + i0 + ci];
    }
    for (int k = 0; k < Kn; k++) {
#pragma unroll
      for (int p = 0; p < 4; p++)
        tile[rj + p * 8][ci] = av[p] * cv[p][k];
      __syncthreads();
#pragma unroll
      for (int p = 0; p < 4; p++) {
        int i = i0 + rj + p * 8;  // ci now indexes j
        Wt[((size_t)b * Nn + i) * Rn + (size_t)k * Nn + j0 + ci] = f2bf(tile[ci][rj + p * 8]);
      }
      __syncthreads();
    }
  }
}

// K2: Y_T[b][c][k*Nn + j] = sum_f ThetaT[k][o][f] * x[b][j][f][t],  c = o*Tn + t
__global__ __launch_bounds__(512) void k_prepY(const float* __restrict__ x,
                                               const ushort* __restrict__ ThT,
                                               ushort* __restrict__ Yt) {
  __shared__ ushort ylds[1024 * 32];  // 64 KB: [c_local][j_slot]
  int jt = blockIdx.x, b = blockIdx.y;
  int j0 = jt * 32;
  int tid = threadIdx.x;
  int lane = tid & 63, w = tid >> 6;
  int l15 = lane & 15, l4 = lane >> 4;

  BF8 bfr[4][2][2];
#pragma unroll
  for (int jj = 0; jj < 4; jj++) {
    const float* xp = x + ((size_t)b * Nn + (j0 + w * 4 + jj)) * (Fn * Tn);
#pragma unroll
    for (int ks = 0; ks < 2; ks++)
#pragma unroll
      for (int tf = 0; tf < 2; tf++) {
        int t = tf * 16 + l15;
        int fb = ks * 32 + l4 * 8;
#pragma unroll
        for (int e = 0; e < 8; e++)
          bfr[jj][ks][tf].s[e] = f2bf(xp[(fb + e) * Tn + t]);
      }
  }

  for (int k = 0; k < Kn; k++) {
    for (int h = 0; h < 2; h++) {  // o-half
      BF8 afr[2][2];
#pragma unroll
      for (int o2 = 0; o2 < 2; o2++)
#pragma unroll
        for (int ks = 0; ks < 2; ks++) {
          int o = h * 32 + o2 * 16 + l15;
          afr[o2][ks].q = *(const uint4*)&ThT[((size_t)k * On + o) * Fn + ks * 32 + l4 * 8];
        }
#pragma unroll
      for (int jj = 0; jj < 4; jj++) {
        f32x4 acc[2][2] = {};
#pragma unroll
        for (int ks = 0; ks < 2; ks++)
#pragma unroll
          for (int o2 = 0; o2 < 2; o2++)
#pragma unroll
            for (int tf = 0; tf < 2; tf++)
              acc[o2][tf] = __builtin_amdgcn_mfma_f32_16x16x32_bf16(
                  afr[o2][ks].v, bfr[jj][ks][tf].v, acc[o2][tf], 0, 0, 0);
#pragma unroll
        for (int o2 = 0; o2 < 2; o2++)
#pragma unroll
          for (int tf = 0; tf < 2; tf++)
#pragma unroll
            for (int q = 0; q < 4; q++) {
              int cl = (o2 * 16 + l4 * 4 + q) * Tn + tf * 16 + l15;
              ylds[cl * 32 + w * 4 + jj] = f2bf(acc[o2][tf][q]);
            }
      }
      __syncthreads();
      const uint32_t* yl32 = (const uint32_t*)ylds;
      uint32_t* Yt32 = (uint32_t*)Yt;
      int e = tid & 15, rowst = tid >> 4;
      for (int pass = 0; pass < 32; pass++) {
        int cl = pass * 32 + rowst;
        size_t off = ((size_t)b * Cn + (size_t)(h * 1024 + cl)) * Rn + (size_t)k * Nn + j0;
        Yt32[off / 2 + e] = yl32[cl * 16 + e];
      }
      __syncthreads();
    }
  }
}

// K3: out[b][i][c] = relu( sum_r Wt[b][i][r] * Yt[b][c][r] )
// 256x256 tile, BK=64, 8 waves (2Mx4N), 2-deep K-tile dbuf, 4 phases/tile,
// XOR-swizzled LDS (both-sides), counted vmcnt (never 0), setprio.
// R4 change: MFMA clusters emitted ks-OUTERMOST so dependent acc updates are
// 8 instructions apart (R3 had back-to-back dependent pairs -> pipe stalls).
__global__ __launch_bounds__(512, 2) void k_gemm(const ushort* __restrict__ Wt,
                                                 const ushort* __restrict__ Yt,
                                                 float* __restrict__ out) {
  extern __shared__ __align__(16) ushort smem[];
  ushort* As = smem;           // 2 bufs x 2 halves x 128x64 = 32768 ushorts
  ushort* Bs = smem + 32768;

  int g = blockIdx.x;
  int b = g & 7, slot = g >> 3;
  int i0 = (slot & 3) * 256, c0 = (slot >> 2) * 256;
  int tid = threadIdx.x, lane = tid & 63, w = tid >> 6;
  int l15 = lane & 15, l4 = lane >> 4;
  int wm = w >> 2, wn = w & 3;

  const ushort* Ab = Wt + ((size_t)b * Nn + i0) * Rn;
  const ushort* Bb = Yt + ((size_t)b * Cn + c0) * Rn;

  int srcC = (((lane & 7) ^ (lane >> 3)) * 8);
  int arow0 = w * 8 + (lane >> 3);
  int brow0 = (w >> 2) * 64 + (w & 3) * 8 + (lane >> 3);

  int aL = (wm * 64 + l15) * 64;
  int bL = (wn * 32 + l15) * 64;
  int x7 = l15 & 7;
  int colx0 = ((l4) ^ x7) * 8;
  int colx1 = ((4 + l4) ^ x7) * 8;

  f32x4 acc[8][4] = {};
  BF8 af[4][2], bf[4][2];

#define MFMA_(a_, b_, c_) __builtin_amdgcn_mfma_f32_16x16x32_bf16((a_), (b_), (c_), 0, 0, 0)
#define BAR() asm volatile("s_barrier" ::: "memory")
#define PRIO1 __builtin_amdgcn_s_setprio(1)
#define PRIO0 __builtin_amdgcn_s_setprio(0)

#define STAGE_A(t_, h_) { int bo_ = ((t_) & 1) * 16384 + (h_) * 8192 + w * 512; \
    const ushort* gp_ = Ab + (size_t)(arow0 + (h_) * 64) * Rn + (t_) * 64 + srcC; \
    glds(gp_, As + bo_); \
    glds(gp_ + 128 * (size_t)Rn, As + bo_ + 4096); }
#define STAGE_B(t_, h_) { int bo_ = ((t_) & 1) * 16384 + (h_) * 8192 + w * 512; \
    const ushort* gp_ = Bb + (size_t)(brow0 + (h_) * 32) * Rn + (t_) * 64 + srcC; \
    glds(gp_, Bs + bo_); \
    glds(gp_ + 128 * (size_t)Rn, Bs + bo_ + 4096); }

#define RD_A(mh_) { _Pragma("unroll") for (int m = 0; m < 4; m++) { \
    int ba_ = bufo + (mh_) * 8192 + aL + m * 1024; \
    af[m][0].q = *(const uint4*)&As[ba_ + colx0]; \
    af[m][1].q = *(const uint4*)&As[ba_ + colx1]; } }
#define RD_B(nh_) { _Pragma("unroll") for (int n = 0; n < 2; n++) { \
    int bb_ = bufo + (nh_) * 8192 + bL + n * 1024; \
    bf[(nh_) * 2 + n][0].q = *(const uint4*)&Bs[bb_ + colx0]; \
    bf[(nh_) * 2 + n][1].q = *(const uint4*)&Bs[bb_ + colx1]; } }
// ks OUTER: 8 independent MFMAs between each acc's two updates.
#define MM(mh_, nh_) { _Pragma("unroll") for (int ks = 0; ks < 2; ks++) \
    _Pragma("unroll") for (int m = 0; m < 4; m++) \
      _Pragma("unroll") for (int n = 0; n < 2; n++) { \
        int gm_ = (mh_) * 4 + m, gn_ = (nh_) * 2 + n; \
        acc[gm_][gn_] = MFMA_(af[m][ks].v, bf[gn_][ks].v, acc[gm_][gn_]); } }

#define VMC(n_) asm volatile("s_waitcnt vmcnt(" #n_ ")" ::: "memory")

  // prologue: issue [Ah0(0), Bh0(0), Bh1(0), Ah1(0), Ah0(1)] = 10 loads
  STAGE_A(0, 0); STAGE_B(0, 0); STAGE_B(0, 1); STAGE_A(0, 1); STAGE_A(1, 0);
  VMC(6);   // Ah0(0), Bh0(0) landed
  BAR();

#define TILE(t_, S1_, S2_, W0_, W1_, W3_, LAST_) { \
    int bufo = ((t_) & 1) * 16384; \
    /* P0: quadrant (mh0, nh0) */ \
    RD_A(0); RD_B(0); \
    if (S1_) STAGE_B((t_) + 1, 0); \
    BAR(); \
    PRIO1; MM(0, 0); PRIO0; \
    VMC(W0_); BAR(); \
    /* P1: (mh0, nh1) */ \
    RD_B(1); \
    if (S1_) { STAGE_B((t_) + 1, 1); STAGE_A((t_) + 1, 1); } \
    BAR(); \
    PRIO1; MM(0, 1); PRIO0; \
    VMC(W1_); BAR(); \
    /* P2: (mh1, nh0) */ \
    RD_A(1); \
    if (S2_) STAGE_A((t_) + 2, 0); \
    BAR(); \
    PRIO1; MM(1, 0); PRIO0; \
    BAR(); \
    /* P3: (mh1, nh1) */ \
    PRIO1; MM(1, 1); PRIO0; \
    if (!(LAST_)) { VMC(W3_); BAR(); } \
  }

  for (int t = 0; t < NT - 2; ++t)
    TILE(t, 1, 1, 6, 8, 6, 0);
  TILE(NT - 2, 1, 0, 6, 8, 4, 0);
  TILE(NT - 1, 0, 0, 2, 0, 0, 1);

#undef TILE
#undef VMC
#undef MM
#undef RD_B
#undef RD_A
#undef STAGE_B
#undef STAGE_A

  float* ob = out + (size_t)b * Nn * Cn;
#pragma unroll
  for (int m = 0; m < 8; m++) {
    int i = i0 + wm * 128 + m * 16 + l4 * 4;
#pragma unroll
    for (int n = 0; n < 4; n++) {
      int c = c0 + wn * 64 + n * 16 + l15;
#pragma unroll
      for (int q = 0; q < 4; q++)
        ob[(size_t)(i + q) * Cn + c] = fmaxf(acc[m][n][q], 0.0f);
    }
  }
}

extern "C" void kernel_launch(void* const* d_in, const int* in_sizes, int n_in,
                              void* d_out, int out_size, void* d_ws, size_t ws_size,
                              hipStream_t stream) {
  const float* x     = (const float*)d_in[0];  // (B,N,F,T)
  const float* att   = (const float*)d_in[1];  // (B,N,N)
  const float* cheb  = (const float*)d_in[2];  // (K,N,N)
  const float* Theta = (const float*)d_in[3];  // (K,F,O)
  float* out = (float*)d_out;                  // (B,N,O,T)

  char* ws = (char*)d_ws;
  ushort* ThT = (ushort*)ws;                              // 24 KB (padded to 64 KB)
  ushort* Wt  = (ushort*)(ws + 65536);                    // 8*1024*3072*2 = 50,331,648 B
  ushort* Yt  = (ushort*)(ws + 65536 + 50331648ull);      // 8*2048*3072*2 = 100,663,296 B

  hipFuncSetAttribute((const void*)k_gemm, hipFuncAttributeMaxDynamicSharedMemorySize, 131072);

  k_thetaT<<<48, 256, 0, stream>>>(Theta, ThT);
  k_prepW<<<dim3(32, 32), 256, 0, stream>>>(att, cheb, Wt);
  k_prepY<<<dim3(32, 8), 512, 0, stream>>>(x, ThT, Yt);
  k_gemm<<<256, 512, 131072, stream>>>(Wt, Yt, out);
}

// Round 5
// 155.583 us; speedup vs baseline: 1.1282x; 1.1168x over previous
//
#include <hip/hip_runtime.h>
#include <stdint.h>

#define Bn 8
#define Nn 1024
#define Fn 64
#define Tn 32
#define Kn 3
#define On 64
#define Rn (Kn * Nn)   // 3072 reduction dim (k,j)
#define Cn (On * Tn)   // 2048 output cols (o,t)
#define NT (Rn / 64)   // 48 K-tiles of BK=64

typedef __bf16 bf16x8 __attribute__((ext_vector_type(8)));
typedef float f32x4 __attribute__((ext_vector_type(4)));
typedef __attribute__((address_space(1))) void gvoid;
typedef __attribute__((address_space(3))) void lvoid;

union BF8 { bf16x8 v; ushort s[8]; uint4 q; };

static __device__ __forceinline__ ushort f2bf(float f) {
  uint32_t u = __float_as_uint(f);
  return (ushort)((u + 0x7FFFu + ((u >> 16) & 1u)) >> 16);
}

static __device__ __forceinline__ void glds(const ushort* g, ushort* l) {
  __builtin_amdgcn_global_load_lds((gvoid*)g, (lvoid*)l, 16, 0, 0);
}

// K0: ThetaT[k][o][f] = Theta[k][f][o], bf16
__global__ void k_thetaT(const float* __restrict__ Theta, ushort* __restrict__ ThT) {
  int idx = blockIdx.x * 256 + threadIdx.x;
  if (idx < Kn * On * Fn) {
    int k = idx / (On * Fn);
    int rem = idx % (On * Fn);
    int o = rem / Fn, f = rem % Fn;
    ThT[idx] = f2bf(Theta[(k * Fn + f) * On + o]);
  }
}

// K1: W_T[b][i][k*Nn + j] = cheb[k][j][i] * att[b][j][i], bf16.
__global__ __launch_bounds__(256) void k_prepW(const float* __restrict__ att,
                                               const float* __restrict__ cheb,
                                               ushort* __restrict__ Wt) {
  __shared__ float tile[32][33];
  int i0 = blockIdx.x * 32, j0 = blockIdx.y * 32;
  int tid = threadIdx.x;
  int ci = tid & 31, rj = tid >> 5;
  float cv[4][Kn];
#pragma unroll
  for (int p = 0; p < 4; p++) {
    int j = j0 + rj + p * 8;
#pragma unroll
    for (int k = 0; k < Kn; k++)
      cv[p][k] = cheb[((size_t)k * Nn + j) * Nn + i0 + ci];
  }
  for (int b = 0; b < Bn; b++) {
    float av[4];
#pragma unroll
    for (int p = 0; p < 4; p++) {
      int j = j0 + rj + p * 8;
      av[p] = att[((size_t)b * Nn + j) * Nn + i0 + ci];
    }
    for (int k = 0; k < Kn; k++) {
#pragma unroll
      for (int p = 0; p < 4; p++)
        tile[rj + p * 8][ci] = av[p] * cv[p][k];
      __syncthreads();
#pragma unroll
      for (int p = 0; p < 4; p++) {
        int i = i0 + rj + p * 8;
        Wt[((size_t)b * Nn + i) * Rn + (size_t)k * Nn + j0 + ci] = f2bf(tile[ci][rj + p * 8]);
      }
      __syncthreads();
    }
  }
}

// K2: Y_T[b][c][k*Nn + j] = sum_f ThetaT[k][o][f] * x[b][j][f][t],  c = o*Tn + t
__global__ __launch_bounds__(512) void k_prepY(const float* __restrict__ x,
                                               const ushort* __restrict__ ThT,
                                               ushort* __restrict__ Yt) {
  __shared__ ushort ylds[1024 * 32];
  int jt = blockIdx.x, b = blockIdx.y;
  int j0 = jt * 32;
  int tid = threadIdx.x;
  int lane = tid & 63, w = tid >> 6;
  int l15 = lane & 15, l4 = lane >> 4;

  BF8 bfr[4][2][2];
#pragma unroll
  for (int jj = 0; jj < 4; jj++) {
    const float* xp = x + ((size_t)b * Nn + (j0 + w * 4 + jj)) * (Fn * Tn);
#pragma unroll
    for (int ks = 0; ks < 2; ks++)
#pragma unroll
      for (int tf = 0; tf < 2; tf++) {
        int t = tf * 16 + l15;
        int fb = ks * 32 + l4 * 8;
#pragma unroll
        for (int e = 0; e < 8; e++)
          bfr[jj][ks][tf].s[e] = f2bf(xp[(fb + e) * Tn + t]);
      }
  }

  for (int k = 0; k < Kn; k++) {
    for (int h = 0; h < 2; h++) {
      BF8 afr[2][2];
#pragma unroll
      for (int o2 = 0; o2 < 2; o2++)
#pragma unroll
        for (int ks = 0; ks < 2; ks++) {
          int o = h * 32 + o2 * 16 + l15;
          afr[o2][ks].q = *(const uint4*)&ThT[((size_t)k * On + o) * Fn + ks * 32 + l4 * 8];
        }
#pragma unroll
      for (int jj = 0; jj < 4; jj++) {
        f32x4 acc[2][2] = {};
#pragma unroll
        for (int ks = 0; ks < 2; ks++)
#pragma unroll
          for (int o2 = 0; o2 < 2; o2++)
#pragma unroll
            for (int tf = 0; tf < 2; tf++)
              acc[o2][tf] = __builtin_amdgcn_mfma_f32_16x16x32_bf16(
                  afr[o2][ks].v, bfr[jj][ks][tf].v, acc[o2][tf], 0, 0, 0);
#pragma unroll
        for (int o2 = 0; o2 < 2; o2++)
#pragma unroll
          for (int tf = 0; tf < 2; tf++)
#pragma unroll
            for (int q = 0; q < 4; q++) {
              int cl = (o2 * 16 + l4 * 4 + q) * Tn + tf * 16 + l15;
              ylds[cl * 32 + w * 4 + jj] = f2bf(acc[o2][tf][q]);
            }
      }
      __syncthreads();
      const uint32_t* yl32 = (const uint32_t*)ylds;
      uint32_t* Yt32 = (uint32_t*)Yt;
      int e = tid & 15, rowst = tid >> 4;
      for (int pass = 0; pass < 32; pass++) {
        int cl = pass * 32 + rowst;
        size_t off = ((size_t)b * Cn + (size_t)(h * 1024 + cl)) * Rn + (size_t)k * Nn + j0;
        Yt32[off / 2 + e] = yl32[cl * 16 + e];
      }
      __syncthreads();
    }
  }
}

// K3: 256x256 tile, BK=64, 8 waves (2Mx4N), 2-deep K-tile dbuf, XOR-swizzled LDS.
// R5: fragment double-buffering — ds_reads issued ONE PHASE EARLY so LDS returns
// overlap the MFMA cluster (R3/R4 serialized: 2260 cyc LDS + 2484 cyc MFMA/tile).
// 3 barriers/tile (was 8), counted vmcnt (never 0), setprio around MFMA.
__global__ __launch_bounds__(512, 2) void k_gemm(const ushort* __restrict__ Wt,
                                                 const ushort* __restrict__ Yt,
                                                 float* __restrict__ out) {
  extern __shared__ __align__(16) ushort smem[];
  ushort* As = smem;           // 2 bufs x 2 halves x 128x64
  ushort* Bs = smem + 32768;

  int g = blockIdx.x;
  int b = g & 7, slot = g >> 3;
  int i0 = (slot & 3) * 256, c0 = (slot >> 2) * 256;
  int tid = threadIdx.x, lane = tid & 63, w = tid >> 6;
  int l15 = lane & 15, l4 = lane >> 4;
  int wm = w >> 2, wn = w & 3;

  const ushort* Ab = Wt + ((size_t)b * Nn + i0) * Rn;
  const ushort* Bb = Yt + ((size_t)b * Cn + c0) * Rn;

  int srcC = (((lane & 7) ^ (lane >> 3)) * 8);
  int arow0 = w * 8 + (lane >> 3);
  int brow0 = (w >> 2) * 64 + (w & 3) * 8 + (lane >> 3);

  int aL = (wm * 64 + l15) * 64;
  int bL = (wn * 32 + l15) * 64;
  int x7 = l15 & 7;
  int colx0 = ((l4) ^ x7) * 8;
  int colx1 = ((4 + l4) ^ x7) * 8;

  f32x4 acc[8][4] = {};
  BF8 afX[4][2], afY[4][2];   // A mh0 / mh1 frag sets
  BF8 bfX[2][2], bfY[2][2];   // B nh0 / nh1 frag sets

#define MFMA_(a_, b_, c_) __builtin_amdgcn_mfma_f32_16x16x32_bf16((a_), (b_), (c_), 0, 0, 0)
#define BAR() asm volatile("s_barrier" ::: "memory")
#define PRIO1 __builtin_amdgcn_s_setprio(1)
#define PRIO0 __builtin_amdgcn_s_setprio(0)
#define VMC(n_) asm volatile("s_waitcnt vmcnt(" #n_ ")" ::: "memory")

#define STAGE_A(t_, h_) { int bo_ = ((t_) & 1) * 16384 + (h_) * 8192 + w * 512; \
    const ushort* gp_ = Ab + (size_t)(arow0 + (h_) * 64) * Rn + (t_) * 64 + srcC; \
    glds(gp_, As + bo_); \
    glds(gp_ + 128 * (size_t)Rn, As + bo_ + 4096); }
#define STAGE_B(t_, h_) { int bo_ = ((t_) & 1) * 16384 + (h_) * 8192 + w * 512; \
    const ushort* gp_ = Bb + (size_t)(brow0 + (h_) * 32) * Rn + (t_) * 64 + srcC; \
    glds(gp_, Bs + bo_); \
    glds(gp_ + 128 * (size_t)Rn, Bs + bo_ + 4096); }

#define RD_A(DST_, bo_, mh_) { _Pragma("unroll") for (int m = 0; m < 4; m++) { \
    int ba_ = (bo_) + (mh_) * 8192 + aL + m * 1024; \
    DST_[m][0].q = *(const uint4*)&As[ba_ + colx0]; \
    DST_[m][1].q = *(const uint4*)&As[ba_ + colx1]; } }
#define RD_B(DST_, bo_, nh_) { _Pragma("unroll") for (int n = 0; n < 2; n++) { \
    int bb_ = (bo_) + (nh_) * 8192 + bL + n * 1024; \
    DST_[n][0].q = *(const uint4*)&Bs[bb_ + colx0]; \
    DST_[n][1].q = *(const uint4*)&Bs[bb_ + colx1]; } }

#define MMC(AF_, BF_, MO_, NO_) { _Pragma("unroll") for (int ks = 0; ks < 2; ks++) \
    _Pragma("unroll") for (int m = 0; m < 4; m++) \
      _Pragma("unroll") for (int n = 0; n < 2; n++) \
        acc[(MO_) + m][(NO_) + n] = MFMA_(AF_[m][ks].v, BF_[n][ks].v, acc[(MO_) + m][(NO_) + n]); }

  // prologue: 10 loads; wait A0(0),B0(0); pre-read them into afX/bfX.
  STAGE_A(0, 0); STAGE_B(0, 0); STAGE_B(0, 1); STAGE_A(0, 1); STAGE_A(1, 0);
  VMC(6); BAR();
  RD_A(afX, 0, 0); RD_B(bfX, 0, 0);

  // per-tile: P0 reads B1(t) during MM(0,0); P1 reads A1(t) during MM(0,1);
  // P3 waits+reads A0,B0(t+1) during MM(1,1). vmcnt queue traced in journal.
#define TILE(t_, S0_, S1_, S2_, W0_, W1_, W3_, LAST_) { \
    int bo_c = ((t_) & 1) * 16384; \
    VMC(W0_); BAR(); \
    RD_B(bfY, bo_c, 1); \
    if (S0_) STAGE_B((t_) + 1, 0); \
    PRIO1; MMC(afX, bfX, 0, 0); PRIO0; \
    VMC(W1_); BAR(); \
    RD_A(afY, bo_c, 1); \
    if (S1_) { STAGE_B((t_) + 1, 1); STAGE_A((t_) + 1, 1); } \
    PRIO1; MMC(afX, bfY, 0, 2); PRIO0; \
    if (S2_) STAGE_A((t_) + 2, 0); \
    PRIO1; MMC(afY, bfX, 4, 0); PRIO0; \
    if (!(LAST_)) { VMC(W3_); BAR(); \
      RD_A(afX, bo_c ^ 16384, 0); RD_B(bfX, bo_c ^ 16384, 0); } \
    PRIO1; MMC(afY, bfY, 4, 2); PRIO0; \
  }

  for (int t = 0; t < NT - 2; ++t)
    TILE(t, 1, 1, 1, 4, 4, 6, 0);
  TILE(NT - 2, 1, 1, 0, 4, 4, 4, 0);
  TILE(NT - 1, 0, 0, 0, 2, 0, 0, 1);

#undef TILE
#undef MMC
#undef RD_B
#undef RD_A
#undef STAGE_B
#undef STAGE_A
#undef VMC

  float* ob = out + (size_t)b * Nn * Cn;
#pragma unroll
  for (int m = 0; m < 8; m++) {
    int i = i0 + wm * 128 + m * 16 + l4 * 4;
#pragma unroll
    for (int n = 0; n < 4; n++) {
      int c = c0 + wn * 64 + n * 16 + l15;
#pragma unroll
      for (int q = 0; q < 4; q++)
        ob[(size_t)(i + q) * Cn + c] = fmaxf(acc[m][n][q], 0.0f);
    }
  }
}

extern "C" void kernel_launch(void* const* d_in, const int* in_sizes, int n_in,
                              void* d_out, int out_size, void* d_ws, size_t ws_size,
                              hipStream_t stream) {
  const float* x     = (const float*)d_in[0];  // (B,N,F,T)
  const float* att   = (const float*)d_in[1];  // (B,N,N)
  const float* cheb  = (const float*)d_in[2];  // (K,N,N)
  const float* Theta = (const float*)d_in[3];  // (K,F,O)
  float* out = (float*)d_out;                  // (B,N,O,T)

  char* ws = (char*)d_ws;
  ushort* ThT = (ushort*)ws;
  ushort* Wt  = (ushort*)(ws + 65536);
  ushort* Yt  = (ushort*)(ws + 65536 + 50331648ull);

  hipFuncSetAttribute((const void*)k_gemm, hipFuncAttributeMaxDynamicSharedMemorySize, 131072);

  k_thetaT<<<48, 256, 0, stream>>>(Theta, ThT);
  k_prepW<<<dim3(32, 32), 256, 0, stream>>>(att, cheb, Wt);
  k_prepY<<<dim3(32, 8), 512, 0, stream>>>(x, ThT, Yt);
  k_gemm<<<256, 512, 131072, stream>>>(Wt, Yt, out);
}